// Round 5
// baseline (140.207 us; speedup 1.0000x reference)
//
#include <hip/hip_runtime.h>
#include <hip/hip_bf16.h>
#include <math.h>

typedef __bf16 bf16_t;
typedef __attribute__((ext_vector_type(8))) __bf16 bf16x8;
typedef __attribute__((ext_vector_type(4))) float f32x4;
typedef __attribute__((ext_vector_type(16))) float f32x16;
typedef __attribute__((ext_vector_type(4))) unsigned u32x4;

#define AS1(p) ((__attribute__((address_space(1))) void*)(p))
#define AS3(p) ((__attribute__((address_space(3))) void*)(p))

// ---------------- f32 -> bf16 convert, 8 elems/thread ----------------
__global__ void cvt_f32_bf16(const float* __restrict__ in, bf16_t* __restrict__ out, int n8) {
  int i = blockIdx.x * blockDim.x + threadIdx.x;
  if (i >= n8) return;
  const float4* p = (const float4*)in;
  float4 a = p[2 * i], b = p[2 * i + 1];
  bf16x8 o;
  o[0] = (bf16_t)a.x; o[1] = (bf16_t)a.y; o[2] = (bf16_t)a.z; o[3] = (bf16_t)a.w;
  o[4] = (bf16_t)b.x; o[5] = (bf16_t)b.y; o[6] = (bf16_t)b.z; o[7] = (bf16_t)b.w;
  ((bf16x8*)out)[i] = o;
}

// ---------------- RoPE tables: cos/sin [2048][32] f32 ----------------
__global__ void rope_tables_k(float* __restrict__ cosb, float* __restrict__ sinb) {
  int t = blockIdx.x * 256 + threadIdx.x;  // 65536 threads
  int s = t >> 5, i = t & 31;
  float inv = powf(10000.0f, -(float)i / 32.0f);
  float ang = (float)s * inv;
  float sv, cv;
  sincosf(ang, &sv, &cv);
  cosb[t] = cv;
  sinb[t] = sv;
}

// ---------------- pack: rope Q in-place (scaled), K -> swizzled tiles, V -> V^T in-place ----
__global__ __launch_bounds__(256)
void pack_rope(bf16_t* __restrict__ qkv, const float* __restrict__ cosb,
               const float* __restrict__ sinb, bf16_t* __restrict__ Kp) {
  __shared__ bf16_t vl[64][72];
  const int t = blockIdx.x, bh = blockIdx.y, b = bh >> 4, h = bh & 15;
  const int tid = threadIdx.x;
  const int r = tid >> 2, j = tid & 3;
  const int s = t * 64 + r;
  bf16_t* base = qkv + ((size_t)(b * 2048 + s)) * 3072 + h * 64;
  const float* cb = cosb + s * 32 + j * 8;
  const float* sb = sinb + s * 32 + j * 8;
  bf16x8 q1 = *(const bf16x8*)(base + j * 8);
  bf16x8 q2 = *(const bf16x8*)(base + j * 8 + 32);
  bf16x8 k1 = *(const bf16x8*)(base + 1024 + j * 8);
  bf16x8 k2 = *(const bf16x8*)(base + 1024 + j * 8 + 32);
  bf16x8 v1 = *(const bf16x8*)(base + 2048 + j * 8);
  bf16x8 v2 = *(const bf16x8*)(base + 2048 + j * 8 + 32);
  const float QS = 0.125f * 1.4426950408889634f;  // 1/sqrt(64) * log2(e)
  bf16x8 qo1, qo2, ko1, ko2;
#pragma unroll
  for (int i = 0; i < 8; ++i) {
    float c = cb[i], sn = sb[i];
    float a1 = (float)q1[i], a2 = (float)q2[i];
    qo1[i] = (bf16_t)((a1 * c - a2 * sn) * QS);
    qo2[i] = (bf16_t)((a2 * c + a1 * sn) * QS);
    float b1 = (float)k1[i], b2 = (float)k2[i];
    ko1[i] = (bf16_t)(b1 * c - b2 * sn);
    ko2[i] = (bf16_t)(b2 * c + b1 * sn);
  }
  *(bf16x8*)(base + j * 8) = qo1;
  *(bf16x8*)(base + j * 8 + 32) = qo2;
  bf16_t* kd = Kp + ((size_t)(bh * 32 + t)) * 4096 + r * 64;
  *(bf16x8*)(kd + ((j ^ (r & 7)) * 8)) = ko1;
  *(bf16x8*)(kd + (((j + 4) ^ (r & 7)) * 8)) = ko2;
#pragma unroll
  for (int i = 0; i < 8; ++i) { vl[r][j * 8 + i] = v1[i]; vl[r][j * 8 + 32 + i] = v2[i]; }
  __syncthreads();
  const int d = r;
  bf16x8 o1, o2;
#pragma unroll
  for (int i = 0; i < 8; ++i) { o1[i] = vl[j * 16 + i][d]; o2[i] = vl[j * 16 + 8 + i][d]; }
  bf16_t* vd = base + 2048;
  *(bf16x8*)(vd + (((2 * j) ^ (d & 7)) * 8)) = o1;
  *(bf16x8*)(vd + (((2 * j + 1) ^ (d & 7)) * 8)) = o2;
}

// ---------------- GEMM C[M,N] = A[M,K] * B[N,K]^T, 128x128 tile, BK=64, XCD swizzle ----
template <typename OutT>
__global__ __launch_bounds__(256, 2)
void gemm_nt(const bf16_t* __restrict__ A, const bf16_t* __restrict__ B,
             OutT* __restrict__ C, int M, int N, int K) {
  __shared__ __align__(16) bf16_t lA[128 * 64];
  __shared__ __align__(16) bf16_t lB[128 * 64];
  const int tid = threadIdx.x;
  const int wid = tid >> 6, lane = tid & 63;
  const int lr = lane & 15, lg = lane >> 4;
  const int nwg = gridDim.x * gridDim.y;
  int lin = blockIdx.y * gridDim.x + blockIdx.x;
  lin = (lin & 7) * (nwg >> 3) + (lin >> 3);
  const int m0 = (lin / gridDim.x) * 128, n0 = (lin % gridDim.x) * 128;
  const int wm = (wid >> 1) * 64, wn = (wid & 1) * 64;
  const int srow = lane >> 3;
  const int scol = (lane & 7) * 8;
  f32x4 acc[4][4];
#pragma unroll
  for (int i = 0; i < 4; ++i)
#pragma unroll
    for (int j = 0; j < 4; ++j) acc[i][j] = f32x4{0.f, 0.f, 0.f, 0.f};

  const int nk = K >> 6;
  for (int kt = 0; kt < nk; ++kt) {
    const int k0 = kt << 6;
    __syncthreads();
#pragma unroll
    for (int i = 0; i < 4; ++i) {
      int c = (wid << 2) + i;
      int r = (c << 3) + srow;
      __builtin_amdgcn_global_load_lds(AS1(A + (size_t)(m0 + r) * K + k0 + scol),
                                       AS3(&lA[c * 512]), 16, 0, 0);
      __builtin_amdgcn_global_load_lds(AS1(B + (size_t)(n0 + r) * K + k0 + scol),
                                       AS3(&lB[c * 512]), 16, 0, 0);
    }
    __syncthreads();
#pragma unroll
    for (int ks = 0; ks < 2; ++ks) {
      bf16x8 af[4], bfr[4];
#pragma unroll
      for (int i = 0; i < 4; ++i) {
        af[i]  = *(const bf16x8*)&lA[(wm + i * 16 + lr) * 64 + ks * 32 + lg * 8];
        bfr[i] = *(const bf16x8*)&lB[(wn + i * 16 + lr) * 64 + ks * 32 + lg * 8];
      }
#pragma unroll
      for (int i = 0; i < 4; ++i)
#pragma unroll
        for (int j = 0; j < 4; ++j)
          acc[i][j] = __builtin_amdgcn_mfma_f32_16x16x32_bf16(af[i], bfr[j], acc[i][j], 0, 0, 0);
    }
  }
#pragma unroll
  for (int i = 0; i < 4; ++i)
#pragma unroll
    for (int j = 0; j < 4; ++j)
#pragma unroll
      for (int r = 0; r < 4; ++r) {
        int row = m0 + wm + i * 16 + lg * 4 + r;
        int col = n0 + wn + j * 16 + lr;
        C[(size_t)row * N + col] = (OutT)acc[i][j][r];
      }
}

// ---------------- flash attention v4: 32x32 MFMA, in-register P (permlane), no P-LDS ----
// 128 thr (2 waves x 32 q-rows), QBLK=64, KVBLK=64. Block: chunk c then 31-c (33 items).
__device__ inline unsigned pkbf(float a, float b) {
  bf16_t x = (bf16_t)a, y = (bf16_t)b;
  return (unsigned)__builtin_bit_cast(unsigned short, x) |
         ((unsigned)__builtin_bit_cast(unsigned short, y) << 16);
}
__device__ inline f32x16 zero16() {
  f32x16 z;
#pragma unroll
  for (int r = 0; r < 16; ++r) z[r] = 0.f;
  return z;
}

__global__ __launch_bounds__(128, 1)
void attn_fwd(const bf16_t* __restrict__ qkv, const bf16_t* __restrict__ Kp,
              bf16_t* __restrict__ O) {
  __shared__ __align__(16) bf16_t Ksh[2][4096];
  __shared__ __align__(16) bf16_t Vsh[2][4096];
  const int tid = threadIdx.x, wid = tid >> 6, lane = tid & 63;
  const int ln = lane & 31, h = lane >> 5;
  const int lin = blockIdx.y * 16 + blockIdx.x;   // same bh -> same lin%8 -> same XCD
  const int c = (lin >> 3) & 15;
  const int bh = (lin & 7) | ((lin >> 7) << 3);
  const int b = bh >> 4, hd = bh & 15;
  const int cA = c, cB = 31 - c;
  const int NI = 33;

  // Q fragments (B-operand: lane holds q-row ln, d-elems 16t+8h..+8), both chunks
  const bf16_t* QArow = qkv + ((size_t)(b * 2048 + cA * 64 + wid * 32 + ln)) * 3072 + hd * 64;
  const bf16_t* QBrow = qkv + ((size_t)(b * 2048 + cB * 64 + wid * 32 + ln)) * 3072 + hd * 64;
  bf16x8 qA[4], qB[4], qc[4];
#pragma unroll
  for (int t = 0; t < 4; ++t) {
    qA[t] = *(const bf16x8*)(QArow + t * 16 + h * 8);
    qB[t] = *(const bf16x8*)(QBrow + t * 16 + h * 8);
    qc[t] = qA[t];
  }
  int qwc = cA * 64 + wid * 32;

  f32x16 o0 = zero16(), o1 = zero16();
  float lp = 0.f;

  const bf16_t* Kbase = Kp + ((size_t)bh * 32) * 4096 + tid * 8;
  const bf16_t* Vbase = qkv + ((size_t)(b * 2048 + (tid >> 3))) * 3072 + 2048 + hd * 64 + (tid & 7) * 8;

#define TILE_OF(IT) ((IT) <= c ? (IT) : (IT) - (c + 1))
#define STAGE(IT, BUF)                                                                    \
  do {                                                                                    \
    int _t = TILE_OF(IT);                                                                 \
    const bf16_t* ks = Kbase + (size_t)_t * 4096;                                         \
    __builtin_amdgcn_global_load_lds(AS1(ks),        AS3(&Ksh[BUF][tid * 8]), 16, 0, 0);  \
    __builtin_amdgcn_global_load_lds(AS1(ks + 1024), AS3(&Ksh[BUF][1024 + tid * 8]), 16, 0, 0); \
    __builtin_amdgcn_global_load_lds(AS1(ks + 2048), AS3(&Ksh[BUF][2048 + tid * 8]), 16, 0, 0); \
    __builtin_amdgcn_global_load_lds(AS1(ks + 3072), AS3(&Ksh[BUF][3072 + tid * 8]), 16, 0, 0); \
    const bf16_t* vs = Vbase + (size_t)_t * 64 * 3072;                                    \
    __builtin_amdgcn_global_load_lds(AS1(vs),             AS3(&Vsh[BUF][tid * 8]), 16, 0, 0);        \
    __builtin_amdgcn_global_load_lds(AS1(vs + 16 * 3072), AS3(&Vsh[BUF][1024 + tid * 8]), 16, 0, 0); \
    __builtin_amdgcn_global_load_lds(AS1(vs + 32 * 3072), AS3(&Vsh[BUF][2048 + tid * 8]), 16, 0, 0); \
    __builtin_amdgcn_global_load_lds(AS1(vs + 48 * 3072), AS3(&Vsh[BUF][3072 + tid * 8]), 16, 0, 0); \
  } while (0)

  STAGE(0, 0);
  for (int i = 0; i < NI; ++i) {
    asm volatile("s_waitcnt vmcnt(0)" ::: "memory");  // own stage(i) loads done
    __builtin_amdgcn_s_barrier();                     // all waves staged; prev buf free
    if (i + 1 < NI) STAGE(i + 1, (i + 1) & 1);        // lands under this item's compute
    const bf16_t* K = &Ksh[i & 1][0];
    const bf16_t* V = &Vsh[i & 1][0];
    // QK^T swapped: S^T = mfma(K, Q): lane holds q-col (ln), kv rows per reg
    f32x16 s0 = zero16(), s1 = zero16();
    __builtin_amdgcn_s_setprio(1);
#pragma unroll
    for (int t = 0; t < 4; ++t) {
      const int ch = 2 * t + h;
      bf16x8 k0 = *(const bf16x8*)&K[ln * 64 + ((ch ^ (ln & 7)) * 8)];
      bf16x8 k1 = *(const bf16x8*)&K[(32 + ln) * 64 + ((ch ^ (ln & 7)) * 8)];
      s0 = __builtin_amdgcn_mfma_f32_32x32x16_bf16(k0, qc[t], s0, 0, 0, 0);
      s1 = __builtin_amdgcn_mfma_f32_32x32x16_bf16(k1, qc[t], s1, 0, 0, 0);
    }
    __builtin_amdgcn_s_setprio(0);
    if (i == c || i == NI - 1) {  // diagonal tile of current phase
      int qg = qwc + ln;
      int k0g = TILE_OF(i) * 64;
#pragma unroll
      for (int r = 0; r < 16; ++r) {
        int kv = k0g + (r & 3) + 8 * (r >> 2) + 4 * h;
        if (kv > qg) s0[r] = -3e38f;
        if (kv + 32 > qg) s1[r] = -3e38f;
      }
    }
    // no-max softmax, fully lane-local (q-col is lane-resident)
#pragma unroll
    for (int r = 0; r < 16; ++r) {
      float p0 = __builtin_amdgcn_exp2f(s0[r]); lp += p0; s0[r] = p0;
      float p1 = __builtin_amdgcn_exp2f(s1[r]); lp += p1; s1[r] = p1;
    }
    // PV: O^T = mfma(V^T, P); P B-frags rebuilt in-register via pack+permlane32_swap
    __builtin_amdgcn_s_setprio(1);
#pragma unroll
    for (int t = 0; t < 4; ++t) {
      const int u = t & 1;
      f32x16 sv = (t >> 1) ? s1 : s0;
      unsigned x  = pkbf(sv[8 * u + 0], sv[8 * u + 1]);
      unsigned x2 = pkbf(sv[8 * u + 2], sv[8 * u + 3]);
      unsigned y  = pkbf(sv[8 * u + 4], sv[8 * u + 5]);
      unsigned y2 = pkbf(sv[8 * u + 6], sv[8 * u + 7]);
      asm volatile("v_permlane32_swap_b32 %0, %1" : "+v"(x), "+v"(y));
      asm volatile("v_permlane32_swap_b32 %0, %1" : "+v"(x2), "+v"(y2));
      u32x4 pw; pw[0] = x; pw[1] = x2; pw[2] = y; pw[3] = y2;
      bf16x8 pf = __builtin_bit_cast(bf16x8, pw);
      const int ch = 2 * t + h;
      bf16x8 v0 = *(const bf16x8*)&V[ln * 64 + ((ch ^ (ln & 7)) * 8)];
      bf16x8 v1 = *(const bf16x8*)&V[(32 + ln) * 64 + ((ch ^ (ln & 7)) * 8)];
      o0 = __builtin_amdgcn_mfma_f32_32x32x16_bf16(v0, pf, o0, 0, 0, 0);
      o1 = __builtin_amdgcn_mfma_f32_32x32x16_bf16(v1, pf, o1, 0, 0, 0);
    }
    __builtin_amdgcn_s_setprio(0);
    if (i == c) {  // phase A done: normalize+store, reset, switch to chunk B
      float lpf = lp + __shfl_xor(lp, 32, 64);
      float inv = 1.0f / lpf;
      bf16_t* Oaddr = O + ((size_t)(b * 2048 + qwc + ln)) * 1024 + hd * 64;
#pragma unroll
      for (int D = 0; D < 2; ++D) {
        f32x16 ov = D ? o1 : o0;
#pragma unroll
        for (int Q = 0; Q < 4; ++Q) {
          uint2 w;
          w.x = pkbf(ov[4 * Q + 0] * inv, ov[4 * Q + 1] * inv);
          w.y = pkbf(ov[4 * Q + 2] * inv, ov[4 * Q + 3] * inv);
          *(uint2*)(Oaddr + D * 32 + Q * 8 + 4 * h) = w;
        }
      }
      o0 = zero16(); o1 = zero16(); lp = 0.f;
#pragma unroll
      for (int t = 0; t < 4; ++t) qc[t] = qB[t];
      qwc = cB * 64 + wid * 32;
    }
  }
#undef STAGE
#undef TILE_OF
  // phase B epilogue
  {
    float lpf = lp + __shfl_xor(lp, 32, 64);
    float inv = 1.0f / lpf;
    bf16_t* Oaddr = O + ((size_t)(b * 2048 + qwc + ln)) * 1024 + hd * 64;
#pragma unroll
    for (int D = 0; D < 2; ++D) {
      f32x16 ov = D ? o1 : o0;
#pragma unroll
      for (int Q = 0; Q < 4; ++Q) {
        uint2 w;
        w.x = pkbf(ov[4 * Q + 0] * inv, ov[4 * Q + 1] * inv);
        w.y = pkbf(ov[4 * Q + 2] * inv, ov[4 * Q + 3] * inv);
        *(uint2*)(Oaddr + D * 32 + Q * 8 + 4 * h) = w;
      }
    }
  }
}

extern "C" void kernel_launch(void* const* d_in, const int* in_sizes, int n_in,
                              void* d_out, int out_size, void* d_ws, size_t ws_size,
                              hipStream_t stream) {
  const float* hid  = (const float*)d_in[0];   // [4096,1024]
  const float* wqkv = (const float*)d_in[1];   // [3072,1024]
  const float* wo   = (const float*)d_in[2];   // [1024,1024]
  float* out = (float*)d_out;                  // [4096,1024] f32
  char* ws = (char*)d_ws;
  bf16_t* hidb  = (bf16_t*)(ws);                  // 0..8M (freed after QKV GEMM)
  bf16_t* wqkvb = (bf16_t*)(ws + 8388608);        // 8M..14M
  bf16_t* wob   = (bf16_t*)(ws + 14680064);       // 14M..16M
  bf16_t* qkvb  = (bf16_t*)(ws + 16777216);       // 16M..40M
  float*  cosb  = (float*)(ws + 41943040);
  float*  sinb  = (float*)(ws + 42205184);
  bf16_t* Ob    = (bf16_t*)(ws + 42467328);       // total 50,855,936 B
  bf16_t* Kp    = (bf16_t*)(ws);                  // reuses hidb slot (8M)

  cvt_f32_bf16<<<2048, 256, 0, stream>>>(hid, hidb, 524288);
  cvt_f32_bf16<<<1536, 256, 0, stream>>>(wqkv, wqkvb, 393216);
  cvt_f32_bf16<<<512, 256, 0, stream>>>(wo, wob, 131072);
  rope_tables_k<<<256, 256, 0, stream>>>(cosb, sinb);
  gemm_nt<bf16_t><<<dim3(24, 32), 256, 0, stream>>>(hidb, wqkvb, qkvb, 4096, 3072, 1024);
  pack_rope<<<dim3(32, 32), 256, 0, stream>>>(qkvb, cosb, sinb, Kp);
  attn_fwd<<<dim3(16, 32), 128, 0, stream>>>(qkvb, Kp, Ob);
  gemm_nt<float><<<dim3(8, 32), 256, 0, stream>>>(Ob, wob, out, 4096, 1024, 1024);
}

// Round 6
// 121.962 us; speedup vs baseline: 1.1496x; 1.1496x over previous
//
#include <hip/hip_runtime.h>
#include <hip/hip_bf16.h>
#include <math.h>

typedef __bf16 bf16_t;
typedef __attribute__((ext_vector_type(8))) __bf16 bf16x8;
typedef __attribute__((ext_vector_type(4))) float f32x4;
typedef __attribute__((ext_vector_type(16))) float f32x16;
typedef __attribute__((ext_vector_type(4))) unsigned u32x4;

#define AS1(p) ((__attribute__((address_space(1))) void*)(p))
#define AS3(p) ((__attribute__((address_space(3))) void*)(p))

__device__ inline void cvt8(const float* __restrict__ in, bf16_t* __restrict__ out, int i) {
  const float4* p = (const float4*)in;
  float4 a = p[2 * i], b = p[2 * i + 1];
  bf16x8 o;
  o[0] = (bf16_t)a.x; o[1] = (bf16_t)a.y; o[2] = (bf16_t)a.z; o[3] = (bf16_t)a.w;
  o[4] = (bf16_t)b.x; o[5] = (bf16_t)b.y; o[6] = (bf16_t)b.z; o[7] = (bf16_t)b.w;
  ((bf16x8*)out)[i] = o;
}

// ---------------- fused prep: 3x f32->bf16 cvt + RoPE tables ----------------
__global__ __launch_bounds__(256)
void prep_all(const float* __restrict__ hid, const float* __restrict__ wqkv,
              const float* __restrict__ wo, bf16_t* __restrict__ hidb,
              bf16_t* __restrict__ wqkvb, bf16_t* __restrict__ wob,
              float* __restrict__ cosb, float* __restrict__ sinb) {
  const int bid = blockIdx.x, tid = threadIdx.x;
  if (bid < 2048) {
    cvt8(hid, hidb, bid * 256 + tid);
  } else if (bid < 3584) {
    cvt8(wqkv, wqkvb, (bid - 2048) * 256 + tid);
  } else if (bid < 4096) {
    cvt8(wo, wob, (bid - 3584) * 256 + tid);
  } else {
    int t = (bid - 4096) * 256 + tid;  // 65536 entries: [2048][32]
    int s = t >> 5, i = t & 31;
    float inv = powf(10000.0f, -(float)i / 32.0f);
    float sv, cv;
    sincosf((float)s * inv, &sv, &cv);
    cosb[t] = cv;
    sinb[t] = sv;
  }
}

// ---------------- pack: rope Q in-place (scaled), K -> swizzled tiles, V -> V^T in-place ----
__global__ __launch_bounds__(256)
void pack_rope(bf16_t* __restrict__ qkv, const float* __restrict__ cosb,
               const float* __restrict__ sinb, bf16_t* __restrict__ Kp) {
  __shared__ bf16_t vl[64][72];
  const int t = blockIdx.x, bh = blockIdx.y, b = bh >> 4, h = bh & 15;
  const int tid = threadIdx.x;
  const int r = tid >> 2, j = tid & 3;
  const int s = t * 64 + r;
  bf16_t* base = qkv + ((size_t)(b * 2048 + s)) * 3072 + h * 64;
  const float* cb = cosb + s * 32 + j * 8;
  const float* sb = sinb + s * 32 + j * 8;
  bf16x8 q1 = *(const bf16x8*)(base + j * 8);
  bf16x8 q2 = *(const bf16x8*)(base + j * 8 + 32);
  bf16x8 k1 = *(const bf16x8*)(base + 1024 + j * 8);
  bf16x8 k2 = *(const bf16x8*)(base + 1024 + j * 8 + 32);
  bf16x8 v1 = *(const bf16x8*)(base + 2048 + j * 8);
  bf16x8 v2 = *(const bf16x8*)(base + 2048 + j * 8 + 32);
  const float QS = 0.125f * 1.4426950408889634f;  // 1/sqrt(64) * log2(e)
  bf16x8 qo1, qo2, ko1, ko2;
#pragma unroll
  for (int i = 0; i < 8; ++i) {
    float c = cb[i], sn = sb[i];
    float a1 = (float)q1[i], a2 = (float)q2[i];
    qo1[i] = (bf16_t)((a1 * c - a2 * sn) * QS);
    qo2[i] = (bf16_t)((a2 * c + a1 * sn) * QS);
    float b1 = (float)k1[i], b2 = (float)k2[i];
    ko1[i] = (bf16_t)(b1 * c - b2 * sn);
    ko2[i] = (bf16_t)(b2 * c + b1 * sn);
  }
  *(bf16x8*)(base + j * 8) = qo1;
  *(bf16x8*)(base + j * 8 + 32) = qo2;
  bf16_t* kd = Kp + ((size_t)(bh * 32 + t)) * 4096 + r * 64;
  *(bf16x8*)(kd + ((j ^ (r & 7)) * 8)) = ko1;
  *(bf16x8*)(kd + (((j + 4) ^ (r & 7)) * 8)) = ko2;
#pragma unroll
  for (int i = 0; i < 8; ++i) { vl[r][j * 8 + i] = v1[i]; vl[r][j * 8 + 32 + i] = v2[i]; }
  __syncthreads();
  const int d = r;
  bf16x8 o1, o2;
#pragma unroll
  for (int i = 0; i < 8; ++i) { o1[i] = vl[j * 16 + i][d]; o2[i] = vl[j * 16 + 8 + i][d]; }
  bf16_t* vd = base + 2048;
  *(bf16x8*)(vd + (((2 * j) ^ (d & 7)) * 8)) = o1;
  *(bf16x8*)(vd + (((2 * j + 1) ^ (d & 7)) * 8)) = o2;
}

// ---------------- GEMM C[M,N] = A[M,K] * B[N,K]^T, 128x128 tile, BK=64, XCD swizzle ----
template <typename OutT>
__global__ __launch_bounds__(256, 2)
void gemm_nt(const bf16_t* __restrict__ A, const bf16_t* __restrict__ B,
             OutT* __restrict__ C, int M, int N, int K) {
  __shared__ __align__(16) bf16_t lA[128 * 64];
  __shared__ __align__(16) bf16_t lB[128 * 64];
  const int tid = threadIdx.x;
  const int wid = tid >> 6, lane = tid & 63;
  const int lr = lane & 15, lg = lane >> 4;
  const int nwg = gridDim.x * gridDim.y;
  int lin = blockIdx.y * gridDim.x + blockIdx.x;
  lin = (lin & 7) * (nwg >> 3) + (lin >> 3);
  const int m0 = (lin / gridDim.x) * 128, n0 = (lin % gridDim.x) * 128;
  const int wm = (wid >> 1) * 64, wn = (wid & 1) * 64;
  const int srow = lane >> 3;
  const int scol = (lane & 7) * 8;
  f32x4 acc[4][4];
#pragma unroll
  for (int i = 0; i < 4; ++i)
#pragma unroll
    for (int j = 0; j < 4; ++j) acc[i][j] = f32x4{0.f, 0.f, 0.f, 0.f};

  const int nk = K >> 6;
  for (int kt = 0; kt < nk; ++kt) {
    const int k0 = kt << 6;
    __syncthreads();
#pragma unroll
    for (int i = 0; i < 4; ++i) {
      int c = (wid << 2) + i;
      int r = (c << 3) + srow;
      __builtin_amdgcn_global_load_lds(AS1(A + (size_t)(m0 + r) * K + k0 + scol),
                                       AS3(&lA[c * 512]), 16, 0, 0);
      __builtin_amdgcn_global_load_lds(AS1(B + (size_t)(n0 + r) * K + k0 + scol),
                                       AS3(&lB[c * 512]), 16, 0, 0);
    }
    __syncthreads();
#pragma unroll
    for (int ks = 0; ks < 2; ++ks) {
      bf16x8 af[4], bfr[4];
#pragma unroll
      for (int i = 0; i < 4; ++i) {
        af[i]  = *(const bf16x8*)&lA[(wm + i * 16 + lr) * 64 + ks * 32 + lg * 8];
        bfr[i] = *(const bf16x8*)&lB[(wn + i * 16 + lr) * 64 + ks * 32 + lg * 8];
      }
#pragma unroll
      for (int i = 0; i < 4; ++i)
#pragma unroll
        for (int j = 0; j < 4; ++j)
          acc[i][j] = __builtin_amdgcn_mfma_f32_16x16x32_bf16(af[i], bfr[j], acc[i][j], 0, 0, 0);
    }
  }
#pragma unroll
  for (int i = 0; i < 4; ++i)
#pragma unroll
    for (int j = 0; j < 4; ++j)
#pragma unroll
      for (int r = 0; r < 4; ++r) {
        int row = m0 + wm + i * 16 + lg * 4 + r;
        int col = n0 + wn + j * 16 + lr;
        C[(size_t)row * N + col] = (OutT)acc[i][j][r];
      }
}

// ---------------- flash attention v5: 32x32 MFMA, in-register P, occupancy-fixed ----
// 1024 blocks x 128 thr (2 waves x 32 q-rows). Block = one 64-row chunk c (NI=c+1 tiles).
__device__ inline unsigned pkbf(float a, float b) {
  bf16_t x = (bf16_t)a, y = (bf16_t)b;
  return (unsigned)__builtin_bit_cast(unsigned short, x) |
         ((unsigned)__builtin_bit_cast(unsigned short, y) << 16);
}
__device__ inline f32x16 zero16() {
  f32x16 z;
#pragma unroll
  for (int r = 0; r < 16; ++r) z[r] = 0.f;
  return z;
}

__global__ __launch_bounds__(128, 2)
void attn_fwd(const bf16_t* __restrict__ qkv, const bf16_t* __restrict__ Kp,
              bf16_t* __restrict__ O) {
  __shared__ __align__(16) bf16_t Ksh[2][4096];
  __shared__ __align__(16) bf16_t Vsh[2][4096];
  const int tid = threadIdx.x, wid = tid >> 6, lane = tid & 63;
  const int ln = lane & 31, h = lane >> 5;
  // boustrophedon chunk order: each CU's 4 resident blocks sum to 66 items;
  // bh = lin&31 keeps same-bh blocks on one XCD's L2 (consecutive lin round-robin XCDs)
  const int lin = blockIdx.x;
  const int g = lin >> 8, j = lin & 255;
  const int bh = j & 31, cc = j >> 5;
  const int c = (g == 0) ? 31 - cc : (g == 1) ? 16 + cc : (g == 2) ? 15 - cc : cc;
  const int b = bh >> 4, hd = bh & 15;
  const int NI = c + 1;
  const int qw = c * 64 + wid * 32;

  // Q fragments (B-operand: lane holds q-row qw+ln, d-elems 16t+8h..+8)
  const bf16_t* Qrow = qkv + ((size_t)(b * 2048 + qw + ln)) * 3072 + hd * 64;
  bf16x8 qf[4];
#pragma unroll
  for (int t = 0; t < 4; ++t) qf[t] = *(const bf16x8*)(Qrow + t * 16 + h * 8);

  f32x16 o0 = zero16(), o1 = zero16();
  float lp = 0.f;

  const bf16_t* Kbase = Kp + ((size_t)bh * 32) * 4096 + tid * 8;
  const bf16_t* Vbase = qkv + ((size_t)(b * 2048 + (tid >> 3))) * 3072 + 2048 + hd * 64 + (tid & 7) * 8;

#define STAGE(T, BUF)                                                                     \
  do {                                                                                    \
    const bf16_t* ks = Kbase + (size_t)(T) * 4096;                                        \
    __builtin_amdgcn_global_load_lds(AS1(ks),        AS3(&Ksh[BUF][tid * 8]), 16, 0, 0);  \
    __builtin_amdgcn_global_load_lds(AS1(ks + 1024), AS3(&Ksh[BUF][1024 + tid * 8]), 16, 0, 0); \
    __builtin_amdgcn_global_load_lds(AS1(ks + 2048), AS3(&Ksh[BUF][2048 + tid * 8]), 16, 0, 0); \
    __builtin_amdgcn_global_load_lds(AS1(ks + 3072), AS3(&Ksh[BUF][3072 + tid * 8]), 16, 0, 0); \
    const bf16_t* vs = Vbase + (size_t)(T) * 64 * 3072;                                   \
    __builtin_amdgcn_global_load_lds(AS1(vs),             AS3(&Vsh[BUF][tid * 8]), 16, 0, 0);        \
    __builtin_amdgcn_global_load_lds(AS1(vs + 16 * 3072), AS3(&Vsh[BUF][1024 + tid * 8]), 16, 0, 0); \
    __builtin_amdgcn_global_load_lds(AS1(vs + 32 * 3072), AS3(&Vsh[BUF][2048 + tid * 8]), 16, 0, 0); \
    __builtin_amdgcn_global_load_lds(AS1(vs + 48 * 3072), AS3(&Vsh[BUF][3072 + tid * 8]), 16, 0, 0); \
  } while (0)

  STAGE(0, 0);
  for (int i = 0; i < NI; ++i) {
    asm volatile("s_waitcnt vmcnt(0)" ::: "memory");  // stage(i) loads done
    __builtin_amdgcn_s_barrier();                     // all waves staged; prev buf free
    if (i + 1 < NI) STAGE(i + 1, (i + 1) & 1);        // lands under this item's compute
    const bf16_t* K = &Ksh[i & 1][0];
    const bf16_t* V = &Vsh[i & 1][0];
    // QK^T swapped: S^T = mfma(K, Q): lane holds q-col (ln), kv rows per reg
    f32x16 s0 = zero16(), s1 = zero16();
    __builtin_amdgcn_s_setprio(1);
#pragma unroll
    for (int t = 0; t < 4; ++t) {
      const int ch = 2 * t + h;
      bf16x8 k0 = *(const bf16x8*)&K[ln * 64 + ((ch ^ (ln & 7)) * 8)];
      bf16x8 k1 = *(const bf16x8*)&K[(32 + ln) * 64 + ((ch ^ (ln & 7)) * 8)];
      s0 = __builtin_amdgcn_mfma_f32_32x32x16_bf16(k0, qf[t], s0, 0, 0, 0);
      s1 = __builtin_amdgcn_mfma_f32_32x32x16_bf16(k1, qf[t], s1, 0, 0, 0);
    }
    __builtin_amdgcn_s_setprio(0);
    if (i == NI - 1) {  // diagonal tile
      const int qg = qw + ln, k0g = i * 64;
#pragma unroll
      for (int r = 0; r < 16; ++r) {
        int kv = k0g + (r & 3) + 8 * (r >> 2) + 4 * h;
        if (kv > qg) s0[r] = -3e38f;
        if (kv + 32 > qg) s1[r] = -3e38f;
      }
    }
    // no-max softmax, fully lane-local (q-col is lane-resident)
#pragma unroll
    for (int r = 0; r < 16; ++r) {
      float p0 = __builtin_amdgcn_exp2f(s0[r]); lp += p0; s0[r] = p0;
      float p1 = __builtin_amdgcn_exp2f(s1[r]); lp += p1; s1[r] = p1;
    }
    // PV: O^T = mfma(V^T, P); P B-frags rebuilt in-register via pack+permlane32_swap
    __builtin_amdgcn_s_setprio(1);
#pragma unroll
    for (int t = 0; t < 4; ++t) {
      const int u = t & 1;
      f32x16 sv = (t >> 1) ? s1 : s0;
      unsigned x  = pkbf(sv[8 * u + 0], sv[8 * u + 1]);
      unsigned x2 = pkbf(sv[8 * u + 2], sv[8 * u + 3]);
      unsigned y  = pkbf(sv[8 * u + 4], sv[8 * u + 5]);
      unsigned y2 = pkbf(sv[8 * u + 6], sv[8 * u + 7]);
      asm volatile("v_permlane32_swap_b32 %0, %1" : "+v"(x), "+v"(y));
      asm volatile("v_permlane32_swap_b32 %0, %1" : "+v"(x2), "+v"(y2));
      u32x4 pw; pw[0] = x; pw[1] = x2; pw[2] = y; pw[3] = y2;
      bf16x8 pf = __builtin_bit_cast(bf16x8, pw);
      const int ch = 2 * t + h;
      bf16x8 v0 = *(const bf16x8*)&V[ln * 64 + ((ch ^ (ln & 7)) * 8)];
      bf16x8 v1 = *(const bf16x8*)&V[(32 + ln) * 64 + ((ch ^ (ln & 7)) * 8)];
      o0 = __builtin_amdgcn_mfma_f32_32x32x16_bf16(v0, pf, o0, 0, 0, 0);
      o1 = __builtin_amdgcn_mfma_f32_32x32x16_bf16(v1, pf, o1, 0, 0, 0);
    }
    __builtin_amdgcn_s_setprio(0);
  }
#undef STAGE
  // epilogue: normalize + store O^T frags as [b][s][h][d] rows
  {
    float lpf = lp + __shfl_xor(lp, 32, 64);
    float inv = 1.0f / lpf;
    bf16_t* Oaddr = O + ((size_t)(b * 2048 + qw + ln)) * 1024 + hd * 64;
#pragma unroll
    for (int D = 0; D < 2; ++D) {
      f32x16 ov = D ? o1 : o0;
#pragma unroll
      for (int Q = 0; Q < 4; ++Q) {
        uint2 w;
        w.x = pkbf(ov[4 * Q + 0] * inv, ov[4 * Q + 1] * inv);
        w.y = pkbf(ov[4 * Q + 2] * inv, ov[4 * Q + 3] * inv);
        *(uint2*)(Oaddr + D * 32 + Q * 8 + 4 * h) = w;
      }
    }
  }
}

extern "C" void kernel_launch(void* const* d_in, const int* in_sizes, int n_in,
                              void* d_out, int out_size, void* d_ws, size_t ws_size,
                              hipStream_t stream) {
  const float* hid  = (const float*)d_in[0];   // [4096,1024]
  const float* wqkv = (const float*)d_in[1];   // [3072,1024]
  const float* wo   = (const float*)d_in[2];   // [1024,1024]
  float* out = (float*)d_out;                  // [4096,1024] f32
  char* ws = (char*)d_ws;
  bf16_t* hidb  = (bf16_t*)(ws);                  // 0..8M (freed after QKV GEMM)
  bf16_t* wqkvb = (bf16_t*)(ws + 8388608);        // 8M..14M
  bf16_t* wob   = (bf16_t*)(ws + 14680064);       // 14M..16M
  bf16_t* qkvb  = (bf16_t*)(ws + 16777216);       // 16M..40M
  float*  cosb  = (float*)(ws + 41943040);
  float*  sinb  = (float*)(ws + 42205184);
  bf16_t* Ob    = (bf16_t*)(ws + 42467328);       // total 50,855,936 B
  bf16_t* Kp    = (bf16_t*)(ws);                  // reuses hidb slot (8M)

  prep_all<<<4352, 256, 0, stream>>>(hid, wqkv, wo, hidb, wqkvb, wob, cosb, sinb);
  gemm_nt<bf16_t><<<dim3(24, 32), 256, 0, stream>>>(hidb, wqkvb, qkvb, 4096, 3072, 1024);
  pack_rope<<<dim3(32, 32), 256, 0, stream>>>(qkvb, cosb, sinb, Kp);
  attn_fwd<<<1024, 128, 0, stream>>>(qkvb, Kp, Ob);
  gemm_nt<float><<<dim3(8, 32), 256, 0, stream>>>(Ob, wob, out, 4096, 1024, 1024);
}

// Round 7
// 118.861 us; speedup vs baseline: 1.1796x; 1.0261x over previous
//
#include <hip/hip_runtime.h>
#include <hip/hip_bf16.h>
#include <math.h>

typedef __bf16 bf16_t;
typedef __attribute__((ext_vector_type(8))) __bf16 bf16x8;
typedef __attribute__((ext_vector_type(4))) float f32x4;
typedef __attribute__((ext_vector_type(16))) float f32x16;
typedef __attribute__((ext_vector_type(4))) unsigned u32x4;

#define AS1(p) ((__attribute__((address_space(1))) void*)(p))
#define AS3(p) ((__attribute__((address_space(3))) void*)(p))

__device__ inline void cvt8(const float* __restrict__ in, bf16_t* __restrict__ out, int i) {
  const float4* p = (const float4*)in;
  float4 a = p[2 * i], b = p[2 * i + 1];
  bf16x8 o;
  o[0] = (bf16_t)a.x; o[1] = (bf16_t)a.y; o[2] = (bf16_t)a.z; o[3] = (bf16_t)a.w;
  o[4] = (bf16_t)b.x; o[5] = (bf16_t)b.y; o[6] = (bf16_t)b.z; o[7] = (bf16_t)b.w;
  ((bf16x8*)out)[i] = o;
}

// ---------------- fused prep: 3x f32->bf16 cvt + RoPE tables ----------------
__global__ __launch_bounds__(256)
void prep_all(const float* __restrict__ hid, const float* __restrict__ wqkv,
              const float* __restrict__ wo, bf16_t* __restrict__ hidb,
              bf16_t* __restrict__ wqkvb, bf16_t* __restrict__ wob,
              float* __restrict__ cosb, float* __restrict__ sinb) {
  const int bid = blockIdx.x, tid = threadIdx.x;
  if (bid < 2048) {
    cvt8(hid, hidb, bid * 256 + tid);
  } else if (bid < 3584) {
    cvt8(wqkv, wqkvb, (bid - 2048) * 256 + tid);
  } else if (bid < 4096) {
    cvt8(wo, wob, (bid - 3584) * 256 + tid);
  } else {
    int t = (bid - 4096) * 256 + tid;  // 65536 entries: [2048][32]
    int s = t >> 5, i = t & 31;
    float inv = powf(10000.0f, -(float)i / 32.0f);
    float sv, cv;
    sincosf((float)s * inv, &sv, &cv);
    cosb[t] = cv;
    sinb[t] = sv;
  }
}

// ---------------- pack: rope Q in-place (scaled), K -> swizzled tiles, V -> V^T in-place ----
__global__ __launch_bounds__(256)
void pack_rope(bf16_t* __restrict__ qkv, const float* __restrict__ cosb,
               const float* __restrict__ sinb, bf16_t* __restrict__ Kp) {
  __shared__ bf16_t vl[64][72];
  const int t = blockIdx.x, bh = blockIdx.y, b = bh >> 4, h = bh & 15;
  const int tid = threadIdx.x;
  const int r = tid >> 2, j = tid & 3;
  const int s = t * 64 + r;
  bf16_t* base = qkv + ((size_t)(b * 2048 + s)) * 3072 + h * 64;
  const float* cb = cosb + s * 32 + j * 8;
  const float* sb = sinb + s * 32 + j * 8;
  bf16x8 q1 = *(const bf16x8*)(base + j * 8);
  bf16x8 q2 = *(const bf16x8*)(base + j * 8 + 32);
  bf16x8 k1 = *(const bf16x8*)(base + 1024 + j * 8);
  bf16x8 k2 = *(const bf16x8*)(base + 1024 + j * 8 + 32);
  bf16x8 v1 = *(const bf16x8*)(base + 2048 + j * 8);
  bf16x8 v2 = *(const bf16x8*)(base + 2048 + j * 8 + 32);
  const float QS = 0.125f * 1.4426950408889634f;  // 1/sqrt(64) * log2(e)
  bf16x8 qo1, qo2, ko1, ko2;
#pragma unroll
  for (int i = 0; i < 8; ++i) {
    float c = cb[i], sn = sb[i];
    float a1 = (float)q1[i], a2 = (float)q2[i];
    qo1[i] = (bf16_t)((a1 * c - a2 * sn) * QS);
    qo2[i] = (bf16_t)((a2 * c + a1 * sn) * QS);
    float b1 = (float)k1[i], b2 = (float)k2[i];
    ko1[i] = (bf16_t)(b1 * c - b2 * sn);
    ko2[i] = (bf16_t)(b2 * c + b1 * sn);
  }
  *(bf16x8*)(base + j * 8) = qo1;
  *(bf16x8*)(base + j * 8 + 32) = qo2;
  bf16_t* kd = Kp + ((size_t)(bh * 32 + t)) * 4096 + r * 64;
  *(bf16x8*)(kd + ((j ^ (r & 7)) * 8)) = ko1;
  *(bf16x8*)(kd + (((j + 4) ^ (r & 7)) * 8)) = ko2;
#pragma unroll
  for (int i = 0; i < 8; ++i) { vl[r][j * 8 + i] = v1[i]; vl[r][j * 8 + 32 + i] = v2[i]; }
  __syncthreads();
  const int d = r;
  bf16x8 o1, o2;
#pragma unroll
  for (int i = 0; i < 8; ++i) { o1[i] = vl[j * 16 + i][d]; o2[i] = vl[j * 16 + 8 + i][d]; }
  bf16_t* vd = base + 2048;
  *(bf16x8*)(vd + (((2 * j) ^ (d & 7)) * 8)) = o1;
  *(bf16x8*)(vd + (((2 * j + 1) ^ (d & 7)) * 8)) = o2;
}

// ---------------- GEMM C[M,N] = A[M,K] * B[N,K]^T, 128x128 tile, BK=64, XCD swizzle ----
template <typename OutT>
__global__ __launch_bounds__(256, 2)
void gemm_nt(const bf16_t* __restrict__ A, const bf16_t* __restrict__ B,
             OutT* __restrict__ C, int M, int N, int K) {
  __shared__ __align__(16) bf16_t lA[128 * 64];
  __shared__ __align__(16) bf16_t lB[128 * 64];
  const int tid = threadIdx.x;
  const int wid = tid >> 6, lane = tid & 63;
  const int lr = lane & 15, lg = lane >> 4;
  const int nwg = gridDim.x * gridDim.y;
  int lin = blockIdx.y * gridDim.x + blockIdx.x;
  lin = (lin & 7) * (nwg >> 3) + (lin >> 3);
  const int m0 = (lin / gridDim.x) * 128, n0 = (lin % gridDim.x) * 128;
  const int wm = (wid >> 1) * 64, wn = (wid & 1) * 64;
  const int srow = lane >> 3;
  const int scol = (lane & 7) * 8;
  f32x4 acc[4][4];
#pragma unroll
  for (int i = 0; i < 4; ++i)
#pragma unroll
    for (int j = 0; j < 4; ++j) acc[i][j] = f32x4{0.f, 0.f, 0.f, 0.f};

  const int nk = K >> 6;
  for (int kt = 0; kt < nk; ++kt) {
    const int k0 = kt << 6;
    __syncthreads();
#pragma unroll
    for (int i = 0; i < 4; ++i) {
      int c = (wid << 2) + i;
      int r = (c << 3) + srow;
      __builtin_amdgcn_global_load_lds(AS1(A + (size_t)(m0 + r) * K + k0 + scol),
                                       AS3(&lA[c * 512]), 16, 0, 0);
      __builtin_amdgcn_global_load_lds(AS1(B + (size_t)(n0 + r) * K + k0 + scol),
                                       AS3(&lB[c * 512]), 16, 0, 0);
    }
    __syncthreads();
#pragma unroll
    for (int ks = 0; ks < 2; ++ks) {
      bf16x8 af[4], bfr[4];
#pragma unroll
      for (int i = 0; i < 4; ++i) {
        af[i]  = *(const bf16x8*)&lA[(wm + i * 16 + lr) * 64 + ks * 32 + lg * 8];
        bfr[i] = *(const bf16x8*)&lB[(wn + i * 16 + lr) * 64 + ks * 32 + lg * 8];
      }
#pragma unroll
      for (int i = 0; i < 4; ++i)
#pragma unroll
        for (int j = 0; j < 4; ++j)
          acc[i][j] = __builtin_amdgcn_mfma_f32_16x16x32_bf16(af[i], bfr[j], acc[i][j], 0, 0, 0);
    }
  }
#pragma unroll
  for (int i = 0; i < 4; ++i)
#pragma unroll
    for (int j = 0; j < 4; ++j)
#pragma unroll
      for (int r = 0; r < 4; ++r) {
        int row = m0 + wm + i * 16 + lg * 4 + r;
        int col = n0 + wn + j * 16 + lr;
        C[(size_t)row * N + col] = (OutT)acc[i][j][r];
      }
}

// ---------------- flash attention v6: split-kv for long chunks ----
// 1408 blocks x 128 thr (2 waves x 32 q-rows). Role LUT, longest chains first.
// kind 0: full chunk c (c<20). kind 1/2: half A/B of chunk c (c>=20), bf16 partials.
__device__ inline unsigned pkbf(float a, float b) {
  bf16_t x = (bf16_t)a, y = (bf16_t)b;
  return (unsigned)__builtin_bit_cast(unsigned short, x) |
         ((unsigned)__builtin_bit_cast(unsigned short, y) << 16);
}
__device__ inline f32x16 zero16() {
  f32x16 z;
#pragma unroll
  for (int r = 0; r < 16; ++r) z[r] = 0.f;
  return z;
}

__device__ const unsigned char ROLE_LUT[44] = {
    19, 18, 17, 16,
    15, 95, 159, 158,
    14, 94, 93, 157,
    13, 92, 156, 91, 155, 154,
    12, 90, 89, 153, 152,
    11, 88, 87, 151, 150,
    10, 86, 85, 149, 148,
    9, 84,
    8, 7, 6, 5, 4, 3, 2, 1, 0};

__global__ __launch_bounds__(128, 2)
void attn_fwd(const bf16_t* __restrict__ qkv, const bf16_t* __restrict__ Kp,
              bf16_t* __restrict__ O, bf16_t* __restrict__ Po, float* __restrict__ Plp) {
  __shared__ __align__(16) bf16_t Ksh[2][4096];
  __shared__ __align__(16) bf16_t Vsh[2][4096];
  const int tid = threadIdx.x, wid = tid >> 6, lane = tid & 63;
  const int ln = lane & 31, h = lane >> 5;
  const int lin = blockIdx.x;
  const int e = ROLE_LUT[lin >> 5];           // role, longest chains at low lin
  const int bh = lin & 31;                    // same-bh blocks share XCD (lin%8)
  const int c = e & 31, kind = e >> 6;
  const int b = bh >> 4, hd = bh & 15;
  const int t0 = (kind == 2) ? ((c + 1) >> 1) : 0;
  const int t1 = (kind == 1) ? ((c + 1) >> 1) : c + 1;
  const int qw = c * 64 + wid * 32;

  // Q fragments (B-operand: lane holds q-row qw+ln, d-elems 16t+8h..+8)
  const bf16_t* Qrow = qkv + ((size_t)(b * 2048 + qw + ln)) * 3072 + hd * 64;
  bf16x8 qf[4];
#pragma unroll
  for (int t = 0; t < 4; ++t) qf[t] = *(const bf16x8*)(Qrow + t * 16 + h * 8);

  f32x16 o0 = zero16(), o1 = zero16();
  float lp = 0.f;

  const bf16_t* Kbase = Kp + ((size_t)bh * 32) * 4096 + tid * 8;
  const bf16_t* Vbase = qkv + ((size_t)(b * 2048 + (tid >> 3))) * 3072 + 2048 + hd * 64 + (tid & 7) * 8;

#define STAGE(T, BUF)                                                                     \
  do {                                                                                    \
    const bf16_t* ks = Kbase + (size_t)(T) * 4096;                                        \
    __builtin_amdgcn_global_load_lds(AS1(ks),        AS3(&Ksh[BUF][tid * 8]), 16, 0, 0);  \
    __builtin_amdgcn_global_load_lds(AS1(ks + 1024), AS3(&Ksh[BUF][1024 + tid * 8]), 16, 0, 0); \
    __builtin_amdgcn_global_load_lds(AS1(ks + 2048), AS3(&Ksh[BUF][2048 + tid * 8]), 16, 0, 0); \
    __builtin_amdgcn_global_load_lds(AS1(ks + 3072), AS3(&Ksh[BUF][3072 + tid * 8]), 16, 0, 0); \
    const bf16_t* vs = Vbase + (size_t)(T) * 64 * 3072;                                   \
    __builtin_amdgcn_global_load_lds(AS1(vs),             AS3(&Vsh[BUF][tid * 8]), 16, 0, 0);        \
    __builtin_amdgcn_global_load_lds(AS1(vs + 16 * 3072), AS3(&Vsh[BUF][1024 + tid * 8]), 16, 0, 0); \
    __builtin_amdgcn_global_load_lds(AS1(vs + 32 * 3072), AS3(&Vsh[BUF][2048 + tid * 8]), 16, 0, 0); \
    __builtin_amdgcn_global_load_lds(AS1(vs + 48 * 3072), AS3(&Vsh[BUF][3072 + tid * 8]), 16, 0, 0); \
  } while (0)

  STAGE(t0, t0 & 1);
  for (int t = t0; t < t1; ++t) {
    asm volatile("s_waitcnt vmcnt(0)" ::: "memory");  // stage(t) loads done
    __builtin_amdgcn_s_barrier();                     // all waves staged; prev buf free
    if (t + 1 < t1) STAGE(t + 1, (t + 1) & 1);        // lands under this item's compute
    const bf16_t* K = &Ksh[t & 1][0];
    const bf16_t* V = &Vsh[t & 1][0];
    // QK^T swapped: S^T = mfma(K, Q): lane holds q-col (ln), kv rows per reg
    f32x16 s0 = zero16(), s1 = zero16();
    __builtin_amdgcn_s_setprio(1);
#pragma unroll
    for (int u = 0; u < 4; ++u) {
      const int ch = 2 * u + h;
      bf16x8 k0 = *(const bf16x8*)&K[ln * 64 + ((ch ^ (ln & 7)) * 8)];
      bf16x8 k1 = *(const bf16x8*)&K[(32 + ln) * 64 + ((ch ^ (ln & 7)) * 8)];
      s0 = __builtin_amdgcn_mfma_f32_32x32x16_bf16(k0, qf[u], s0, 0, 0, 0);
      s1 = __builtin_amdgcn_mfma_f32_32x32x16_bf16(k1, qf[u], s1, 0, 0, 0);
    }
    __builtin_amdgcn_s_setprio(0);
    if (t == c) {  // diagonal tile
      const int qg = qw + ln, k0g = t * 64;
#pragma unroll
      for (int r = 0; r < 16; ++r) {
        int kv = k0g + (r & 3) + 8 * (r >> 2) + 4 * h;
        if (kv > qg) s0[r] = -3e38f;
        if (kv + 32 > qg) s1[r] = -3e38f;
      }
    }
    // no-max softmax, fully lane-local (q-col is lane-resident)
#pragma unroll
    for (int r = 0; r < 16; ++r) {
      float p0 = __builtin_amdgcn_exp2f(s0[r]); lp += p0; s0[r] = p0;
      float p1 = __builtin_amdgcn_exp2f(s1[r]); lp += p1; s1[r] = p1;
    }
    // PV: O^T = mfma(V^T, P); P B-frags rebuilt in-register via pack+permlane32_swap
    __builtin_amdgcn_s_setprio(1);
#pragma unroll
    for (int u = 0; u < 4; ++u) {
      const int w = u & 1;
      f32x16 sv = (u >> 1) ? s1 : s0;
      unsigned x  = pkbf(sv[8 * w + 0], sv[8 * w + 1]);
      unsigned x2 = pkbf(sv[8 * w + 2], sv[8 * w + 3]);
      unsigned y  = pkbf(sv[8 * w + 4], sv[8 * w + 5]);
      unsigned y2 = pkbf(sv[8 * w + 6], sv[8 * w + 7]);
      asm volatile("v_permlane32_swap_b32 %0, %1" : "+v"(x), "+v"(y));
      asm volatile("v_permlane32_swap_b32 %0, %1" : "+v"(x2), "+v"(y2));
      u32x4 pw; pw[0] = x; pw[1] = x2; pw[2] = y; pw[3] = y2;
      bf16x8 pf = __builtin_bit_cast(bf16x8, pw);
      const int ch = 2 * u + h;
      bf16x8 v0 = *(const bf16x8*)&V[ln * 64 + ((ch ^ (ln & 7)) * 8)];
      bf16x8 v1 = *(const bf16x8*)&V[(32 + ln) * 64 + ((ch ^ (ln & 7)) * 8)];
      o0 = __builtin_amdgcn_mfma_f32_32x32x16_bf16(v0, pf, o0, 0, 0, 0);
      o1 = __builtin_amdgcn_mfma_f32_32x32x16_bf16(v1, pf, o1, 0, 0, 0);
    }
    __builtin_amdgcn_s_setprio(0);
  }
#undef STAGE
  // epilogue
  float lpf = lp + __shfl_xor(lp, 32, 64);
  if (kind == 0) {  // normalize + store O^T frags as [b][s][h][d] rows
    float inv = 1.0f / lpf;
    bf16_t* Oaddr = O + ((size_t)(b * 2048 + qw + ln)) * 1024 + hd * 64;
#pragma unroll
    for (int D = 0; D < 2; ++D) {
      f32x16 ov = D ? o1 : o0;
#pragma unroll
      for (int Q = 0; Q < 4; ++Q) {
        uint2 w;
        w.x = pkbf(ov[4 * Q + 0] * inv, ov[4 * Q + 1] * inv);
        w.y = pkbf(ov[4 * Q + 2] * inv, ov[4 * Q + 3] * inv);
        *(uint2*)(Oaddr + D * 32 + Q * 8 + 4 * h) = w;
      }
    }
  } else {  // write unnormalized bf16 partials + f32 row-sum
    const int slot = (bh * 12 + (c - 20)) * 2 + (kind - 1);
    const int qi = wid * 32 + ln;
    if (h == 0) Plp[slot * 64 + qi] = lpf;
    bf16_t* Paddr = Po + ((size_t)(slot * 64 + qi)) * 64;
#pragma unroll
    for (int D = 0; D < 2; ++D) {
      f32x16 ov = D ? o1 : o0;
#pragma unroll
      for (int Q = 0; Q < 4; ++Q) {
        uint2 w;
        w.x = pkbf(ov[4 * Q + 0], ov[4 * Q + 1]);
        w.y = pkbf(ov[4 * Q + 2], ov[4 * Q + 3]);
        *(uint2*)(Paddr + D * 32 + Q * 8 + 4 * h) = w;
      }
    }
  }
}

// ---------------- combine split-kv partials: O = (oA+oB)/(lpA+lpB) ----
__global__ __launch_bounds__(64)
void attn_combine(const bf16_t* __restrict__ Po, const float* __restrict__ Plp,
                  bf16_t* __restrict__ O) {
  const int blk = blockIdx.x;  // 384 = bh*12 + sc
  const int bh = blk / 12, sc = blk % 12;
  const int b = bh >> 4, hd = bh & 15;
  const int c = 20 + sc;
  const int q = threadIdx.x;  // 64 q-rows
  const int slotA = (bh * 12 + sc) * 2, slotB = slotA + 1;
  float inv = 1.0f / (Plp[slotA * 64 + q] + Plp[slotB * 64 + q]);
  const bf16x8* pa = (const bf16x8*)(Po + ((size_t)(slotA * 64 + q)) * 64);
  const bf16x8* pb = (const bf16x8*)(Po + ((size_t)(slotB * 64 + q)) * 64);
  bf16_t* oaddr = O + ((size_t)(b * 2048 + c * 64 + q)) * 1024 + hd * 64;
#pragma unroll
  for (int j = 0; j < 8; ++j) {
    bf16x8 a = pa[j], v = pb[j];
    bf16x8 w;
#pragma unroll
    for (int k = 0; k < 8; ++k) w[k] = (bf16_t)(((float)a[k] + (float)v[k]) * inv);
    ((bf16x8*)oaddr)[j] = w;
  }
}

extern "C" void kernel_launch(void* const* d_in, const int* in_sizes, int n_in,
                              void* d_out, int out_size, void* d_ws, size_t ws_size,
                              hipStream_t stream) {
  const float* hid  = (const float*)d_in[0];   // [4096,1024]
  const float* wqkv = (const float*)d_in[1];   // [3072,1024]
  const float* wo   = (const float*)d_in[2];   // [1024,1024]
  float* out = (float*)d_out;                  // [4096,1024] f32
  char* ws = (char*)d_ws;
  bf16_t* hidb  = (bf16_t*)(ws);                  // 0..8M (reused as Kp)
  bf16_t* wqkvb = (bf16_t*)(ws + 8388608);        // 8M..14M (reused as Po)
  bf16_t* wob   = (bf16_t*)(ws + 14680064);       // 14M..16M
  bf16_t* qkvb  = (bf16_t*)(ws + 16777216);       // 16M..40M
  float*  cosb  = (float*)(ws + 41943040);        // reused as Plp
  float*  sinb  = (float*)(ws + 42205184);
  bf16_t* Ob    = (bf16_t*)(ws + 42467328);       // total 50,855,936 B
  bf16_t* Kp    = (bf16_t*)(ws);                  // reuses hidb slot (8M)
  bf16_t* Po    = (bf16_t*)(ws + 8388608);        // reuses wqkvb slot (6,291,456 B exact)
  float*  Plp   = (float*)(ws + 41943040);        // reuses cosb slot (196,608 <= 262,144)

  prep_all<<<4352, 256, 0, stream>>>(hid, wqkv, wo, hidb, wqkvb, wob, cosb, sinb);
  gemm_nt<bf16_t><<<dim3(24, 32), 256, 0, stream>>>(hidb, wqkvb, qkvb, 4096, 3072, 1024);
  pack_rope<<<dim3(32, 32), 256, 0, stream>>>(qkvb, cosb, sinb, Kp);
  attn_fwd<<<1408, 128, 0, stream>>>(qkvb, Kp, Ob, Po, Plp);
  attn_combine<<<384, 64, 0, stream>>>(Po, Plp, Ob);
  gemm_nt<float><<<dim3(8, 32), 256, 0, stream>>>(Ob, wob, out, 4096, 1024, 1024);
}